// Round 5
// baseline (311.625 us; speedup 1.0000x reference)
//
#include <hip/hip_runtime.h>
#include <math.h>

// Problem constants
constexpr int B_  = 2;
constexpr int C_  = 256;
constexpr int CQ_ = 64;
constexpr int N_  = 4096;  // 64*64

typedef __attribute__((ext_vector_type(8))) short     short8;  // 8 bf16
typedef __attribute__((ext_vector_type(8))) _Float16  half8;   // 8 f16
typedef __attribute__((ext_vector_type(4))) float     f32x4;   // MFMA C/D

constexpr float SHIFT = 24.0f;   // static softmax shift (exact: shift-invariance)

static __device__ __forceinline__ unsigned short f2bf(float x) {
    union { float f; unsigned u; } v; v.f = x;
    unsigned r = (v.u + 0x7FFFu + ((v.u >> 16) & 1u)) >> 16;  // RNE
    return (unsigned short)r;
}

static __device__ __forceinline__ half8 cvt_w8(const float* p) {
    float4 f0 = *(const float4*)p;
    float4 f1 = *(const float4*)(p + 4);
    half8 h;
    h[0] = (_Float16)f0.x; h[1] = (_Float16)f0.y;
    h[2] = (_Float16)f0.z; h[3] = (_Float16)f0.w;
    h[4] = (_Float16)f1.x; h[5] = (_Float16)f1.y;
    h[6] = (_Float16)f1.z; h[7] = (_Float16)f1.w;
    return h;
}

// ---------------------------------------------------------------------------
// Fused QKV projection (MFMA, f16, fp32 accum).  W converted on the fly
// (L2-hot).  Per block: one 64-n tile of one bs; z=0 -> Q+K, z=1 -> V.
// Orientation: D rows = contiguous output axis -> packed b64 stores.
//   Q/K: A=W (m=o), B=Xs (col=n) -> D[o][n], store [n][64] packed over o.
//   V:   A=Xs (m=n), B=W (col=c) -> D[n][c], store [c][n] packed over n.
// ---------------------------------------------------------------------------
__global__ __launch_bounds__(512)
void proj_kernel(const float* __restrict__ in1, const float* __restrict__ in2,
                 const float* __restrict__ q1w, const float* __restrict__ q1b,
                 const float* __restrict__ k1w, const float* __restrict__ k1b,
                 const float* __restrict__ v1w, const float* __restrict__ v1b,
                 const float* __restrict__ q2w, const float* __restrict__ q2b,
                 const float* __restrict__ k2w, const float* __restrict__ k2b,
                 const float* __restrict__ v2w, const float* __restrict__ v2b,
                 _Float16* __restrict__ q_ws, _Float16* __restrict__ k_ws,
                 unsigned short* __restrict__ v_ws)
{
    __shared__ _Float16 Xs[64 * 264];
    const int bs = blockIdx.y, s = bs >> 1, bb = bs & 1;
    const int n0 = blockIdx.x * 64;
    const float* x = (s ? in2 : in1) + (size_t)bb * C_ * N_;
    const int tid = threadIdx.x;
    const int lane = tid & 63, wave = tid >> 6, quad = lane >> 4, l15 = lane & 15;

    // stage + transpose + convert X tile (256c x 64n) -> Xs[n][c] f16
    #pragma unroll
    for (int rep = 0; rep < 8; ++rep) {
        int idx = rep * 512 + tid;
        int c = idx >> 4, ng = idx & 15;
        float4 f = *(const float4*)(x + (size_t)c * N_ + n0 + ng * 4);
        Xs[(ng * 4 + 0) * 264 + c] = (_Float16)f.x;
        Xs[(ng * 4 + 1) * 264 + c] = (_Float16)f.y;
        Xs[(ng * 4 + 2) * 264 + c] = (_Float16)f.z;
        Xs[(ng * 4 + 3) * 264 + c] = (_Float16)f.w;
    }
    __syncthreads();

    if (blockIdx.z == 0) {
        // ---- Q/K: waves 0-3 -> Q (nb=wave), waves 4-7 -> K ----
        const int m = wave >> 2, nb = wave & 3;
        const float* W    = m ? (s ? k2w : k1w) : (s ? q2w : q1w);
        const float* bias = m ? (s ? k2b : k1b) : (s ? q2b : q1b);
        _Float16* outp = (m ? k_ws : q_ws) + (size_t)bs * N_ * CQ_;

        half8 bfx[8];
        #pragma unroll
        for (int kh = 0; kh < 8; ++kh)
            bfx[kh] = *(const half8*)(&Xs[(16 * nb + l15) * 264 + quad * 8 + kh * 32]);
        f32x4 acc[4];
        #pragma unroll
        for (int o = 0; o < 4; ++o) acc[o] = (f32x4){0.f, 0.f, 0.f, 0.f};
        #pragma unroll
        for (int kh = 0; kh < 8; ++kh)
            #pragma unroll
            for (int o = 0; o < 4; ++o) {
                half8 aw = cvt_w8(W + (size_t)(16 * o + l15) * C_ + quad * 8 + kh * 32);
                acc[o] = __builtin_amdgcn_mfma_f32_16x16x32_f16(aw, bfx[kh], acc[o], 0, 0, 0);
            }
        int n = n0 + 16 * nb + l15;
        #pragma unroll
        for (int o = 0; o < 4; ++o) {
            float4 bv = *(const float4*)(bias + 16 * o + quad * 4);
            ushort4 u;
            _Float16 h;
            h = (_Float16)(acc[o][0] + bv.x); u.x = *(unsigned short*)&h;
            h = (_Float16)(acc[o][1] + bv.y); u.y = *(unsigned short*)&h;
            h = (_Float16)(acc[o][2] + bv.z); u.z = *(unsigned short*)&h;
            h = (_Float16)(acc[o][3] + bv.w); u.w = *(unsigned short*)&h;
            *(ushort4*)((unsigned short*)outp + (size_t)n * CQ_ + 16 * o + quad * 4) = u;
        }
    } else {
        // ---- V: wave owns c-rows 32*wave .. +31 (oo 0..1) ----
        const float* Wv = (s ? v2w : v1w);
        const float* vb = (s ? v2b : v1b);
        unsigned short* outp = v_ws + (size_t)bs * C_ * N_;
        f32x4 acc[4][2];
        #pragma unroll
        for (int nt = 0; nt < 4; ++nt)
            #pragma unroll
            for (int oo = 0; oo < 2; ++oo) acc[nt][oo] = (f32x4){0.f, 0.f, 0.f, 0.f};
        #pragma unroll
        for (int kh = 0; kh < 8; ++kh) {
            half8 af[4], bw[2];
            #pragma unroll
            for (int nt = 0; nt < 4; ++nt)
                af[nt] = *(const half8*)(&Xs[(16 * nt + l15) * 264 + quad * 8 + kh * 32]);
            #pragma unroll
            for (int oo = 0; oo < 2; ++oo)
                bw[oo] = cvt_w8(Wv + (size_t)(32 * wave + 16 * oo + l15) * C_ + quad * 8 + kh * 32);
            #pragma unroll
            for (int nt = 0; nt < 4; ++nt)
                #pragma unroll
                for (int oo = 0; oo < 2; ++oo)
                    acc[nt][oo] = __builtin_amdgcn_mfma_f32_16x16x32_f16(
                        af[nt], bw[oo], acc[nt][oo], 0, 0, 0);
        }
        #pragma unroll
        for (int oo = 0; oo < 2; ++oo) {
            int c = 32 * wave + 16 * oo + l15;
            float bv = vb[c];
            #pragma unroll
            for (int nt = 0; nt < 4; ++nt) {
                ushort4 u;
                u.x = f2bf(acc[nt][oo][0] + bv);
                u.y = f2bf(acc[nt][oo][1] + bv);
                u.z = f2bf(acc[nt][oo][2] + bv);
                u.w = f2bf(acc[nt][oo][3] + bv);
                *(ushort4*)(outp + (size_t)c * N_ + n0 + 16 * nt + quad * 4) = u;
            }
        }
    }
}

// ---------------------------------------------------------------------------
// MFMA flash attention, static-shift softmax (exact: softmax shift-invariance;
// the gating bias is constant along the softmax axis -> cancels, skipped).
// TQ=32 rows/WG, grid 512 -> 2 WG/CU (latency hiding across barriers).
// K/V frags direct from global (L2-resident per XCD); only P round-trips LDS
// (double-buffered, 1 barrier/iter).
// S: wave -> tile [16j (jb=w&3)][16i (ih=w>>2)].  PV: wave -> 32i x 32c (wc=w).
// ---------------------------------------------------------------------------
constexpr int ST = 72;   // Pt stride (bf16 elems)

__global__ __launch_bounds__(512, 4)
void flash_kernel(const _Float16* __restrict__ qg,        // [bs][n][64] f16
                  const _Float16* __restrict__ kg,        // [bs][n][64] f16
                  const unsigned short* __restrict__ vg,  // [bs][c][n] bf16
                  const float* __restrict__ in1, const float* __restrict__ in2,
                  const float* __restrict__ gamma_p, float* __restrict__ out)
{
    __shared__ unsigned short Pt[2][32 * ST];
    __shared__ float lsum[32 * 4];

    const int tid  = threadIdx.x;
    const int lane = tid & 63;
    const int wave = tid >> 6;
    const int quad = lane >> 4;
    const int l15  = lane & 15;
    const int bs   = blockIdx.x & 3;        // XCD swizzle: bs = xcd & 3
    const int q0   = (blockIdx.x >> 2) * 32;
    const int s = bs >> 1, bb = bs & 1;
    const int jb = wave & 3;
    const int ih = wave >> 2;
    const int wc = wave;                    // PV: c-block 32*wc

    const _Float16* qp = qg + (size_t)bs * N_ * CQ_;
    const _Float16* kp = kg + (size_t)bs * N_ * CQ_;
    const unsigned short* vp = vg + (size_t)bs * C_ * N_;

    // persistent Q B-frags (col = i = q0 + 16*ih + l15)
    half8 qf[2];
    #pragma unroll
    for (int kh = 0; kh < 2; ++kh)
        qf[kh] = *(const half8*)(qp + (size_t)(q0 + 16 * ih + l15) * CQ_ + quad * 8 + kh * 32);

    float lacc = 0.f;
    f32x4 acc[2][2];   // [isub: i=16isub+quad*4+r][csub: c=32wc+16csub+l15]
    #pragma unroll
    for (int a = 0; a < 2; ++a)
        #pragma unroll
        for (int b = 0; b < 2; ++b) acc[a][b] = (f32x4){0.f, 0.f, 0.f, 0.f};

    // K A-frag prefetch for iter 0 (m = j = 16*jb + l15)
    half8 kf[2];
    #pragma unroll
    for (int kh = 0; kh < 2; ++kh)
        kf[kh] = *(const half8*)(kp + (size_t)(16 * jb + l15) * CQ_ + quad * 8 + kh * 32);

    for (int jt = 0; jt < N_; jt += 64) {
        const int pb = (jt >> 6) & 1;
        // V B-frags for this iter (latency overlapped with S + barrier)
        short8 vf[2][2];
        #pragma unroll
        for (int csub = 0; csub < 2; ++csub)
            #pragma unroll
            for (int kh = 0; kh < 2; ++kh)
                vf[csub][kh] = *(const short8*)(
                    vp + (size_t)(32 * wc + 16 * csub + l15) * N_ + jt + quad * 8 + kh * 32);
        // K prefetch for next iter
        int jn = (jt + 64 < N_) ? jt + 64 : 0;
        half8 kn0 = *(const half8*)(kp + (size_t)(jn + 16 * jb + l15) * CQ_ + quad * 8);
        half8 kn1 = *(const half8*)(kp + (size_t)(jn + 16 * jb + l15) * CQ_ + quad * 8 + 32);

        // ---- S: tile [j = 16jb+quad*4+r][i = 16ih+l15] ----
        f32x4 sacc = (f32x4){0.f, 0.f, 0.f, 0.f};
        sacc = __builtin_amdgcn_mfma_f32_16x16x32_f16(kf[0], qf[0], sacc, 0, 0, 0);
        sacc = __builtin_amdgcn_mfma_f32_16x16x32_f16(kf[1], qf[1], sacc, 0, 0, 0);

        // p = exp(s - SHIFT); accumulate l; write P[i][j] (bf16, b64)
        f32x4 p;
        p.x = __expf(sacc.x - SHIFT);
        p.y = __expf(sacc.y - SHIFT);
        p.z = __expf(sacc.z - SHIFT);
        p.w = __expf(sacc.w - SHIFT);
        lacc += p.x + p.y + p.z + p.w;
        ushort4 pbv;
        pbv.x = f2bf(p.x); pbv.y = f2bf(p.y); pbv.z = f2bf(p.z); pbv.w = f2bf(p.w);
        *(ushort4*)(&Pt[pb][(16 * ih + l15) * ST + 16 * jb + quad * 4]) = pbv;
        kf[0] = kn0; kf[1] = kn1;
        __syncthreads();

        // ---- PV: O^T[i = 16isub+quad*4+r][c = 32wc+16csub+l15] ----
        short8 ap[2][2];
        #pragma unroll
        for (int isub = 0; isub < 2; ++isub)
            #pragma unroll
            for (int kh = 0; kh < 2; ++kh)
                ap[isub][kh] = *(const short8*)(
                    &Pt[pb][(16 * isub + l15) * ST + quad * 8 + kh * 32]);
        #pragma unroll
        for (int kh = 0; kh < 2; ++kh)
            #pragma unroll
            for (int isub = 0; isub < 2; ++isub)
                #pragma unroll
                for (int csub = 0; csub < 2; ++csub)
                    acc[isub][csub] = __builtin_amdgcn_mfma_f32_16x16x32_bf16(
                        ap[isub][kh], vf[csub][kh], acc[isub][csub], 0, 0, 0);
    }

    // ---- l reduction (once) ----
    {
        float t = lacc;
        t += __shfl_xor(t, 16);
        t += __shfl_xor(t, 32);
        if (quad == 0) lsum[(16 * ih + l15) * 4 + jb] = t;
    }
    __syncthreads();

    const float gamma = gamma_p[0];
    const float* inp = (s ? in2 : in1) + (size_t)bb * C_ * N_;
    float* op = out + (size_t)bs * C_ * N_;
    #pragma unroll
    for (int isub = 0; isub < 2; ++isub) {
        float inv[4];
        #pragma unroll
        for (int r = 0; r < 4; ++r) {
            f32x4 t = *(f32x4*)(&lsum[(16 * isub + quad * 4 + r) * 4]);
            inv[r] = gamma / (t.x + t.y + t.z + t.w);
        }
        #pragma unroll
        for (int csub = 0; csub < 2; ++csub) {
            int c = 32 * wc + 16 * csub + l15;
            int i0 = q0 + 16 * isub + quad * 4;
            float4 ip = *(const float4*)(inp + (size_t)c * N_ + i0);
            float4 o4;
            o4.x = acc[isub][csub][0] * inv[0] + ip.x;
            o4.y = acc[isub][csub][1] * inv[1] + ip.y;
            o4.z = acc[isub][csub][2] * inv[2] + ip.z;
            o4.w = acc[isub][csub][3] * inv[3] + ip.w;
            *(float4*)(op + (size_t)c * N_ + i0) = o4;
        }
    }
}

// ---------------------------------------------------------------------------
extern "C" void kernel_launch(void* const* d_in, const int* in_sizes, int n_in,
                              void* d_out, int out_size, void* d_ws, size_t ws_size,
                              hipStream_t stream)
{
    const float* in1 = (const float*)d_in[0];
    const float* in2 = (const float*)d_in[1];
    const float* q1w = (const float*)d_in[2];
    const float* q1b = (const float*)d_in[3];
    const float* k1w = (const float*)d_in[4];
    const float* k1b = (const float*)d_in[5];
    const float* v1w = (const float*)d_in[6];
    const float* v1b = (const float*)d_in[7];
    const float* q2w = (const float*)d_in[8];
    const float* q2b = (const float*)d_in[9];
    const float* k2w = (const float*)d_in[10];
    const float* k2b = (const float*)d_in[11];
    const float* v2w = (const float*)d_in[12];
    const float* v2b = (const float*)d_in[13];
    const float* gamma = (const float*)d_in[22];
    float* out = (float*)d_out;

    // ws: q[4][4096][64] f16 | k same | v[4][256][4096] bf16
    _Float16* q_ws = (_Float16*)d_ws;
    _Float16* k_ws = q_ws + (size_t)4 * N_ * CQ_;
    unsigned short* v_ws = (unsigned short*)(k_ws + (size_t)4 * N_ * CQ_);

    proj_kernel<<<dim3(64, 4, 2), 512, 0, stream>>>(
        in1, in2, q1w, q1b, k1w, k1b, v1w, v1b,
        q2w, q2b, k2w, k2b, v2w, v2b, q_ws, k_ws, v_ws);
    flash_kernel<<<dim3(512), 512, 0, stream>>>(q_ws, k_ws, v_ws, in1, in2, gamma, out);
}

// Round 6
// 288.792 us; speedup vs baseline: 1.0791x; 1.0791x over previous
//
#include <hip/hip_runtime.h>
#include <hip/hip_cooperative_groups.h>
#include <math.h>

namespace cg = cooperative_groups;

// Problem constants
constexpr int B_  = 2;
constexpr int C_  = 256;
constexpr int CQ_ = 64;
constexpr int N_  = 4096;  // 64*64

typedef __attribute__((ext_vector_type(8))) short     short8;  // 8 bf16
typedef __attribute__((ext_vector_type(8))) _Float16  half8;   // 8 f16
typedef __attribute__((ext_vector_type(4))) float     f32x4;   // MFMA C/D

constexpr float SHIFT = 24.0f;   // static softmax shift (exact: shift-invariance)

static __device__ __forceinline__ unsigned short f2bf(float x) {
    union { float f; unsigned u; } v; v.f = x;
    unsigned r = (v.u + 0x7FFFu + ((v.u >> 16) & 1u)) >> 16;  // RNE
    return (unsigned short)r;
}
static __device__ __forceinline__ unsigned short f2h(float x) {
    _Float16 h = (_Float16)x;
    return *(unsigned short*)&h;
}
static __device__ __forceinline__ half8 cvt_w8(const float* p) {
    float4 f0 = *(const float4*)p;
    float4 f1 = *(const float4*)(p + 4);
    half8 h;
    h[0] = (_Float16)f0.x; h[1] = (_Float16)f0.y;
    h[2] = (_Float16)f0.z; h[3] = (_Float16)f0.w;
    h[4] = (_Float16)f1.x; h[5] = (_Float16)f1.y;
    h[6] = (_Float16)f1.z; h[7] = (_Float16)f1.w;
    return h;
}

// ---------------------------------------------------------------------------
// One cooperative kernel.  grid = 256 (bs = blk&3 -> XCD L2 affinity,
// tile = blk>>2 : 64-n proj tile == 64-i flash q-tile).  512 thr / 8 waves.
//
// Phase 1 (proj): stage X[256c][64n] fp32 -> Xs[n][c] f16, XOR-swizzled
// (16B chunk ^ (n&31)): staging b64 writes 2-way, frag b128 reads
// conflict-free.  Q/K: waves 0-3/4-7 (A=W on-the-fly f16, B=Xs) -> [n][64].
// V: each wave owns 32 c (A=Xs, B=W) -> [c][n] bf16.
//
// grid.sync()
//
// Phase 2 (flash): static-shift softmax (gating bias is constant along the
// softmax axis -> cancels exactly; branch skipped).  Per iter (64 j):
//   S: wave (jb=w&3, ih=w>>2) -> S^T[16j][32i], A=K-frag (global, pipelined
//      1 iter ahead in regs), B=Q-frag (persistent regs).
//   P: exp -> bf16 -> XOR-swizzled LDS (2-way writes, conflict-free reads),
//      double-buffered.
//   barrier = raw "s_waitcnt lgkmcnt(0); s_barrier" (no vmcnt drain; next
//      iter's K/V loads stay in flight).
//   PV: wave w owns 64i x 32c (V enters CU exactly once), A=P from LDS,
//      B=V-frag (global, pipelined).
// l accumulated per-thread, reduced once at the end.
// ---------------------------------------------------------------------------
__global__ __launch_bounds__(512, 2)
void fused_kernel(const float* __restrict__ in1, const float* __restrict__ in2,
                  const float* __restrict__ q1w, const float* __restrict__ q1b,
                  const float* __restrict__ k1w, const float* __restrict__ k1b,
                  const float* __restrict__ v1w, const float* __restrict__ v1b,
                  const float* __restrict__ q2w, const float* __restrict__ q2b,
                  const float* __restrict__ k2w, const float* __restrict__ k2b,
                  const float* __restrict__ v2w, const float* __restrict__ v2b,
                  const float* __restrict__ gamma_p, float* __restrict__ out,
                  _Float16* __restrict__ q_ws, _Float16* __restrict__ k_ws,
                  unsigned short* __restrict__ v_ws)
{
    __shared__ __align__(16) char smem[33 * 1024];
    const int tid = threadIdx.x;
    const int lane = tid & 63, wave = tid >> 6, quad = lane >> 4, l15 = lane & 15;
    const int blk = blockIdx.x, bs = blk & 3, tile = blk >> 2;
    const int s = bs >> 1, bb = bs & 1;
    const int n0 = tile * 64;

    // ======================== Phase 1: projection =========================
    {
        _Float16* Xs = (_Float16*)smem;   // [n][256c], 16B-chunk ^ (n&31)
        const float* x = (s ? in2 : in1) + (size_t)bb * C_ * N_;

        #pragma unroll
        for (int rep = 0; rep < 2; ++rep) {
            int id = rep * 512 + tid;
            int cq = id >> 4, ng = id & 15;       // c-quad (4c), n-quad (4n)
            const float* xp = x + (size_t)(cq * 4) * N_ + n0 + ng * 4;
            float4 f0 = *(const float4*)(xp);
            float4 f1 = *(const float4*)(xp + N_);
            float4 f2 = *(const float4*)(xp + 2 * N_);
            float4 f3 = *(const float4*)(xp + 3 * N_);
            const float* fr[4] = {(const float*)&f0, (const float*)&f1,
                                  (const float*)&f2, (const float*)&f3};
            #pragma unroll
            for (int w = 0; w < 4; ++w) {
                int n = 4 * ng + w;
                ushort4 u;
                u.x = f2h(fr[0][w]); u.y = f2h(fr[1][w]);
                u.z = f2h(fr[2][w]); u.w = f2h(fr[3][w]);
                int off = n * 256 + (((cq >> 1) ^ (n & 31)) << 3) + ((cq & 1) << 2);
                *(ushort4*)(&Xs[off]) = u;
            }
        }
        __syncthreads();

        // ---- Q/K: waves 0-3 -> Q (nb=wave), 4-7 -> K ----
        {
            const int m = wave >> 2, nb = wave & 3;
            const float* W    = m ? (s ? k2w : k1w) : (s ? q2w : q1w);
            const float* bias = m ? (s ? k2b : k1b) : (s ? q2b : q1b);
            unsigned short* outp =
                (unsigned short*)((m ? k_ws : q_ws) + (size_t)bs * N_ * CQ_);
            const int n = 16 * nb + l15;
            half8 bfx[8];
            #pragma unroll
            for (int kh = 0; kh < 8; ++kh)
                bfx[kh] = *(const half8*)(&Xs[n * 256 + (((quad + 4 * kh) ^ (n & 31)) << 3)]);
            f32x4 a4[4];
            #pragma unroll
            for (int o = 0; o < 4; ++o) a4[o] = (f32x4){0.f, 0.f, 0.f, 0.f};
            #pragma unroll
            for (int kh = 0; kh < 8; ++kh)
                #pragma unroll
                for (int o = 0; o < 4; ++o) {
                    half8 aw = cvt_w8(W + (size_t)(16 * o + l15) * C_ + quad * 8 + kh * 32);
                    a4[o] = __builtin_amdgcn_mfma_f32_16x16x32_f16(aw, bfx[kh], a4[o], 0, 0, 0);
                }
            #pragma unroll
            for (int o = 0; o < 4; ++o) {
                float4 bv = *(const float4*)(bias + 16 * o + quad * 4);
                ushort4 u;
                u.x = f2h(a4[o][0] + bv.x); u.y = f2h(a4[o][1] + bv.y);
                u.z = f2h(a4[o][2] + bv.z); u.w = f2h(a4[o][3] + bv.w);
                *(ushort4*)(outp + (size_t)(n0 + n) * CQ_ + 16 * o + quad * 4) = u;
            }
        }

        // ---- V: wave owns c-rows 32*wave .. +31 ----
        {
            const float* Wv = s ? v2w : v1w;
            const float* vb = s ? v2b : v1b;
            unsigned short* outp = v_ws + (size_t)bs * C_ * N_;
            f32x4 a4[4][2];
            #pragma unroll
            for (int nt = 0; nt < 4; ++nt)
                #pragma unroll
                for (int oo = 0; oo < 2; ++oo) a4[nt][oo] = (f32x4){0.f, 0.f, 0.f, 0.f};
            #pragma unroll
            for (int kh = 0; kh < 8; ++kh) {
                half8 af[4], bw[2];
                #pragma unroll
                for (int nt = 0; nt < 4; ++nt) {
                    int n = 16 * nt + l15;
                    af[nt] = *(const half8*)(&Xs[n * 256 + (((quad + 4 * kh) ^ (n & 31)) << 3)]);
                }
                #pragma unroll
                for (int oo = 0; oo < 2; ++oo)
                    bw[oo] = cvt_w8(Wv + (size_t)(32 * wave + 16 * oo + l15) * C_ + quad * 8 + kh * 32);
                #pragma unroll
                for (int nt = 0; nt < 4; ++nt)
                    #pragma unroll
                    for (int oo = 0; oo < 2; ++oo)
                        a4[nt][oo] = __builtin_amdgcn_mfma_f32_16x16x32_f16(
                            af[nt], bw[oo], a4[nt][oo], 0, 0, 0);
            }
            #pragma unroll
            for (int oo = 0; oo < 2; ++oo) {
                int c = 32 * wave + 16 * oo + l15;
                float bvv = vb[c];
                #pragma unroll
                for (int nt = 0; nt < 4; ++nt) {
                    ushort4 u;
                    u.x = f2bf(a4[nt][oo][0] + bvv);
                    u.y = f2bf(a4[nt][oo][1] + bvv);
                    u.z = f2bf(a4[nt][oo][2] + bvv);
                    u.w = f2bf(a4[nt][oo][3] + bvv);
                    *(ushort4*)(outp + (size_t)c * N_ + n0 + 16 * nt + quad * 4) = u;
                }
            }
        }
    }

    cg::this_grid().sync();

    // ========================= Phase 2: flash =============================
    {
        unsigned short* Pt = (unsigned short*)smem;       // 2 bufs x [64i][64j]
        float* lsum = (float*)(smem + 16384);             // [64i][4jb]
        const int q0 = n0;
        const int jb = wave & 3, ih = wave >> 2, wc = wave;

        const _Float16* qp = q_ws + (size_t)bs * N_ * CQ_;
        const _Float16* kp = k_ws + (size_t)bs * N_ * CQ_;
        const unsigned short* vp = v_ws + (size_t)bs * C_ * N_;

        // persistent Q B-frags (col i = q0 + 32ih + 16isub + l15)
        half8 qf[2][2];
        #pragma unroll
        for (int isub = 0; isub < 2; ++isub)
            #pragma unroll
            for (int kh = 0; kh < 2; ++kh)
                qf[isub][kh] = *(const half8*)(
                    qp + (size_t)(q0 + 32 * ih + 16 * isub + l15) * CQ_ + quad * 8 + kh * 32);

        // pipelined K A-frags and V B-frags (tile 0)
        half8 kf[2];
        #pragma unroll
        for (int kh = 0; kh < 2; ++kh)
            kf[kh] = *(const half8*)(kp + (size_t)(16 * jb + l15) * CQ_ + quad * 8 + kh * 32);
        short8 vf[2][2];
        #pragma unroll
        for (int csub = 0; csub < 2; ++csub)
            #pragma unroll
            for (int kh = 0; kh < 2; ++kh)
                vf[csub][kh] = *(const short8*)(
                    vp + (size_t)(32 * wc + 16 * csub + l15) * N_ + quad * 8 + kh * 32);

        float lacc[2] = {0.f, 0.f};
        f32x4 acc[4][2];   // [isub: i=16isub+quad*4+r][csub: c=32wc+16csub+l15]
        #pragma unroll
        for (int a = 0; a < 4; ++a)
            #pragma unroll
            for (int b = 0; b < 2; ++b) acc[a][b] = (f32x4){0.f, 0.f, 0.f, 0.f};

        for (int t = 0; t < 64; ++t) {
            const int jn = (t + 1 < 64) ? (t + 1) * 64 : 0;
            // issue next-tile loads (consumed next iter; fly across barrier)
            half8 kn[2];
            #pragma unroll
            for (int kh = 0; kh < 2; ++kh)
                kn[kh] = *(const half8*)(
                    kp + (size_t)(jn + 16 * jb + l15) * CQ_ + quad * 8 + kh * 32);
            short8 vn[2][2];
            #pragma unroll
            for (int csub = 0; csub < 2; ++csub)
                #pragma unroll
                for (int kh = 0; kh < 2; ++kh)
                    vn[csub][kh] = *(const short8*)(
                        vp + (size_t)(32 * wc + 16 * csub + l15) * N_ + jn + quad * 8 + kh * 32);

            // ---- S: S^T[j=16jb+quad*4+r][i=32ih+16isub+l15] ----
            f32x4 sacc[2];
            sacc[0] = (f32x4){0.f, 0.f, 0.f, 0.f};
            sacc[1] = (f32x4){0.f, 0.f, 0.f, 0.f};
            #pragma unroll
            for (int kh = 0; kh < 2; ++kh)
                #pragma unroll
                for (int isub = 0; isub < 2; ++isub)
                    sacc[isub] = __builtin_amdgcn_mfma_f32_16x16x32_f16(
                        kf[kh], qf[isub][kh], sacc[isub], 0, 0, 0);

            // p = exp(s-SHIFT) -> bf16 -> swizzled LDS; accumulate l
            unsigned short* Pb = Pt + (t & 1) * 4096;
            #pragma unroll
            for (int isub = 0; isub < 2; ++isub) {
                f32x4 p;
                p.x = __expf(sacc[isub].x - SHIFT);
                p.y = __expf(sacc[isub].y - SHIFT);
                p.z = __expf(sacc[isub].z - SHIFT);
                p.w = __expf(sacc[isub].w - SHIFT);
                lacc[isub] += p.x + p.y + p.z + p.w;
                ushort4 pb;
                pb.x = f2bf(p.x); pb.y = f2bf(p.y); pb.z = f2bf(p.z); pb.w = f2bf(p.w);
                int row = 32 * ih + 16 * isub + l15;
                int off = row * 64 + (((2 * jb + (quad >> 1)) ^ (row & 7)) << 3)
                        + ((quad & 1) << 2);
                *(ushort4*)(&Pb[off]) = pb;
            }

            // LDS-only barrier: no vmcnt drain (K/V prefetch stays in flight)
            asm volatile("s_waitcnt lgkmcnt(0)\n\ts_barrier" ::: "memory");

            // ---- PV: O^T[i=16isub+quad*4+r][c=32wc+16csub+l15] ----
            short8 ap[4][2];
            #pragma unroll
            for (int isub = 0; isub < 4; ++isub)
                #pragma unroll
                for (int kh = 0; kh < 2; ++kh) {
                    int row = 16 * isub + l15;
                    ap[isub][kh] = *(const short8*)(
                        &Pb[row * 64 + (((quad + 4 * kh) ^ (row & 7)) << 3)]);
                }
            #pragma unroll
            for (int kh = 0; kh < 2; ++kh)
                #pragma unroll
                for (int isub = 0; isub < 4; ++isub)
                    #pragma unroll
                    for (int csub = 0; csub < 2; ++csub)
                        acc[isub][csub] = __builtin_amdgcn_mfma_f32_16x16x32_bf16(
                            ap[isub][kh], vf[csub][kh], acc[isub][csub], 0, 0, 0);

            kf[0] = kn[0]; kf[1] = kn[1];
            #pragma unroll
            for (int csub = 0; csub < 2; ++csub)
                #pragma unroll
                for (int kh = 0; kh < 2; ++kh) vf[csub][kh] = vn[csub][kh];
        }

        // ---- l reduction (once) ----
        #pragma unroll
        for (int isub = 0; isub < 2; ++isub) {
            float tq = lacc[isub];
            tq += __shfl_xor(tq, 16);
            tq += __shfl_xor(tq, 32);
            if (quad == 0) lsum[(32 * ih + 16 * isub + l15) * 4 + jb] = tq;
        }
        __syncthreads();

        const float gamma = gamma_p[0];
        const float* inp = (s ? in2 : in1) + (size_t)bb * C_ * N_;
        float* op = out + (size_t)bs * C_ * N_;
        #pragma unroll
        for (int isub = 0; isub < 4; ++isub) {
            float inv[4];
            #pragma unroll
            for (int r = 0; r < 4; ++r) {
                f32x4 tl = *(f32x4*)(&lsum[(16 * isub + quad * 4 + r) * 4]);
                inv[r] = gamma / (tl.x + tl.y + tl.z + tl.w);
            }
            #pragma unroll
            for (int csub = 0; csub < 2; ++csub) {
                int c = 32 * wc + 16 * csub + l15;
                int i0 = q0 + 16 * isub + quad * 4;
                float4 ip = *(const float4*)(inp + (size_t)c * N_ + i0);
                float4 o4;
                o4.x = acc[isub][csub][0] * inv[0] + ip.x;
                o4.y = acc[isub][csub][1] * inv[1] + ip.y;
                o4.z = acc[isub][csub][2] * inv[2] + ip.z;
                o4.w = acc[isub][csub][3] * inv[3] + ip.w;
                *(float4*)(op + (size_t)c * N_ + i0) = o4;
            }
        }
    }
}

// ---------------------------------------------------------------------------
extern "C" void kernel_launch(void* const* d_in, const int* in_sizes, int n_in,
                              void* d_out, int out_size, void* d_ws, size_t ws_size,
                              hipStream_t stream)
{
    const float* in1 = (const float*)d_in[0];
    const float* in2 = (const float*)d_in[1];
    const float* q1w = (const float*)d_in[2];
    const float* q1b = (const float*)d_in[3];
    const float* k1w = (const float*)d_in[4];
    const float* k1b = (const float*)d_in[5];
    const float* v1w = (const float*)d_in[6];
    const float* v1b = (const float*)d_in[7];
    const float* q2w = (const float*)d_in[8];
    const float* q2b = (const float*)d_in[9];
    const float* k2w = (const float*)d_in[10];
    const float* k2b = (const float*)d_in[11];
    const float* v2w = (const float*)d_in[12];
    const float* v2b = (const float*)d_in[13];
    const float* gamma = (const float*)d_in[22];
    float* out = (float*)d_out;

    // ws: q[4][4096][64] f16 | k same | v[4][256][4096] bf16  (12 MB)
    _Float16* q_ws = (_Float16*)d_ws;
    _Float16* k_ws = q_ws + (size_t)4 * N_ * CQ_;
    unsigned short* v_ws = (unsigned short*)(k_ws + (size_t)4 * N_ * CQ_);

    void* args[] = {
        (void*)&in1, (void*)&in2,
        (void*)&q1w, (void*)&q1b, (void*)&k1w, (void*)&k1b,
        (void*)&v1w, (void*)&v1b, (void*)&q2w, (void*)&q2b,
        (void*)&k2w, (void*)&k2b, (void*)&v2w, (void*)&v2b,
        (void*)&gamma, (void*)&out, (void*)&q_ws, (void*)&k_ws, (void*)&v_ws
    };
    hipLaunchCooperativeKernel((void*)fused_kernel, dim3(256), dim3(512),
                               args, 0, stream);
}